// Round 2
// 1029.785 us; speedup vs baseline: 2.4093x; 2.4093x over previous
//
#include <hip/hip_runtime.h>

#define NPTS 1000000
#define CH 128
#define NG 100000
#define SCAN_CHUNK 1024
#define NB ((NG + SCAN_CHUNK - 1) / SCAN_CHUNK)  // 98 blocks of 1024

// ================= fast path: counting sort + per-group reduce =================

__global__ void hist_kernel(const int* __restrict__ gid, int* __restrict__ cnt) {
    int i = blockIdx.x * blockDim.x + threadIdx.x;
    if (i < NPTS) atomicAdd(&cnt[gid[i]], 1);
}

// per-1024-chunk exclusive scan (256 threads x 4 elements), block totals to bsum
__global__ void scan_blocks_kernel(const int* __restrict__ cnt, int* __restrict__ off,
                                   int* __restrict__ bsum) {
    __shared__ int lds[256];
    int t = threadIdx.x;
    int base = blockIdx.x * SCAN_CHUNK + t * 4;
    int a0 = 0, a1 = 0, a2 = 0, a3 = 0;
    if (base + 0 < NG) a0 = cnt[base + 0];
    if (base + 1 < NG) a1 = cnt[base + 1];
    if (base + 2 < NG) a2 = cnt[base + 2];
    if (base + 3 < NG) a3 = cnt[base + 3];
    lds[t] = a0 + a1 + a2 + a3;
    __syncthreads();
    for (int d = 1; d < 256; d <<= 1) {
        int v = (t >= d) ? lds[t - d] : 0;
        __syncthreads();
        lds[t] += v;
        __syncthreads();
    }
    int excl = (t == 0) ? 0 : lds[t - 1];
    if (t == 255) bsum[blockIdx.x] = lds[255];
    if (base + 0 < NG) off[base + 0] = excl;
    if (base + 1 < NG) off[base + 1] = excl + a0;
    if (base + 2 < NG) off[base + 2] = excl + a0 + a1;
    if (base + 3 < NG) off[base + 3] = excl + a0 + a1 + a2;
}

// exclusive scan of the 98 block totals (single block)
__global__ void scan_bsum_kernel(int* __restrict__ bsum) {
    __shared__ int lds[128];
    int t = threadIdx.x;
    int v = (t < NB) ? bsum[t] : 0;
    lds[t] = v;
    __syncthreads();
    for (int d = 1; d < 128; d <<= 1) {
        int u = (t >= d) ? lds[t - d] : 0;
        __syncthreads();
        lds[t] += u;
        __syncthreads();
    }
    int excl = (t == 0) ? 0 : lds[t - 1];
    if (t < NB) bsum[t] = excl;
}

// slot assignment; reads block-local off + scanned block base directly
__global__ void fill_kernel(const int* __restrict__ gid, const int* __restrict__ off,
                            const int* __restrict__ bsum, int* __restrict__ cursor,
                            int* __restrict__ idx) {
    int i = blockIdx.x * blockDim.x + threadIdx.x;
    if (i < NPTS) {
        int g = gid[i];
        int s = atomicAdd(&cursor[g], 1);
        idx[off[g] + bsum[g >> 10] + s] = i;
    }
}

// one 64-lane wave per group; lane owns 2 channels (float2 = 512B/point coalesced).
// Writes the pre-divided mean (no atomics, means buffer needs no zeroing).
__global__ void reduce_kernel(const float* __restrict__ feat, const int* __restrict__ idx,
                              const int* __restrict__ off, const int* __restrict__ bsum,
                              const int* __restrict__ cnt, float* __restrict__ means) {
    long long t = (long long)blockIdx.x * blockDim.x + threadIdx.x;
    int g = (int)(t >> 6);
    int lane = (int)(t & 63);
    if (g >= NG) return;
    int o = off[g] + bsum[g >> 10];
    int n = cnt[g];
    float2 a0 = make_float2(0.f, 0.f), a1 = make_float2(0.f, 0.f);
    int j = 0;
    for (; j + 2 <= n; j += 2) {  // 2-way unroll: 2 independent loads in flight
        int p0 = idx[o + j];
        int p1 = idx[o + j + 1];
        float2 v0 = ((const float2*)(feat + (long long)p0 * CH))[lane];
        float2 v1 = ((const float2*)(feat + (long long)p1 * CH))[lane];
        a0.x += v0.x; a0.y += v0.y;
        a1.x += v1.x; a1.y += v1.y;
    }
    if (j < n) {
        int p = idx[o + j];
        float2 v = ((const float2*)(feat + (long long)p * CH))[lane];
        a0.x += v.x; a0.y += v.y;
    }
    float inv = 1.0f / fmaxf((float)n, 1.0f);
    float2 r = make_float2((a0.x + a1.x) * inv, (a0.y + a1.y) * inv);
    ((float2*)(means + (long long)g * CH))[lane] = r;
}

// 32 threads per point; means are pre-divided -> straight gather/store.
__global__ void gather_mean_kernel(const float* __restrict__ means,
                                   const int* __restrict__ gid,
                                   float* __restrict__ out) {
    long long t = (long long)blockIdx.x * blockDim.x + threadIdx.x;
    int point = (int)(t >> 5);
    int sub = (int)(t & 31);
    if (point >= NPTS) return;
    int g = gid[point];
    float4 v = ((const float4*)(means + (long long)g * CH))[sub];
    ((float4*)(out + (long long)point * CH))[sub] = v;
}

// ================= fallback path (harness-verified atomic version) =================

__global__ void accum_kernel(const float* __restrict__ feat,
                             const int* __restrict__ gid,
                             float* __restrict__ sums,
                             float* __restrict__ counts) {
    long long t = (long long)blockIdx.x * blockDim.x + threadIdx.x;
    int point = (int)(t >> 5);
    int sub = (int)(t & 31);
    if (point >= NPTS) return;
    int g = gid[point];
    const float4 v = ((const float4*)(feat + (long long)point * CH))[sub];
    float* dst = sums + (long long)g * CH + sub * 4;
    atomicAdd(dst + 0, v.x);
    atomicAdd(dst + 1, v.y);
    atomicAdd(dst + 2, v.z);
    atomicAdd(dst + 3, v.w);
    if (sub == 0) atomicAdd(counts + g, 1.0f);
}

__global__ void inv_kernel(float* __restrict__ counts) {
    int g = blockIdx.x * blockDim.x + threadIdx.x;
    if (g < NG) counts[g] = 1.0f / fmaxf(counts[g], 1.0f);
}

__global__ void gather_kernel(const float* __restrict__ sums,
                              const float* __restrict__ inv,
                              const int* __restrict__ gid,
                              float* __restrict__ out) {
    long long t = (long long)blockIdx.x * blockDim.x + threadIdx.x;
    int point = (int)(t >> 5);
    int sub = (int)(t & 31);
    if (point >= NPTS) return;
    int g = gid[point];
    float ic = inv[g];
    float4 v = ((const float4*)(sums + (long long)g * CH))[sub];
    v.x *= ic; v.y *= ic; v.z *= ic; v.w *= ic;
    ((float4*)(out + (long long)point * CH))[sub] = v;
}

// ================= launch =================

extern "C" void kernel_launch(void* const* d_in, const int* in_sizes, int n_in,
                              void* d_out, int out_size, void* d_ws, size_t ws_size,
                              hipStream_t stream) {
    const float* feat = (const float*)d_in[1];
    const int* gid = (const int*)d_in[2];
    float* out = (float*)d_out;

    // fast-path workspace layout (all 4-byte types, base is hipMalloc-aligned)
    char* p = (char*)d_ws;
    float* means = (float*)p;          p += (size_t)NG * CH * sizeof(float);  // 51.2 MB
    int* idx     = (int*)p;            p += (size_t)NPTS * sizeof(int);       //  4.0 MB
    int* cnt     = (int*)p;            p += (size_t)NG * sizeof(int);
    int* off     = (int*)p;            p += (size_t)NG * sizeof(int);
    int* cursor  = (int*)p;            p += (size_t)NG * sizeof(int);
    int* bsum    = (int*)p;            p += 128 * sizeof(int);
    size_t need = (size_t)(p - (char*)d_ws);

    const int block = 256;

    if (ws_size >= need) {
        // zero cnt/off/cursor/bsum (contiguous, ~1.2 MB; means needs no zeroing)
        hipMemsetAsync(cnt, 0, (size_t)NG * sizeof(int) * 3 + 128 * sizeof(int), stream);

        hist_kernel<<<(NPTS + block - 1) / block, block, 0, stream>>>(gid, cnt);
        scan_blocks_kernel<<<NB, 256, 0, stream>>>(cnt, off, bsum);
        scan_bsum_kernel<<<1, 128, 0, stream>>>(bsum);
        fill_kernel<<<(NPTS + block - 1) / block, block, 0, stream>>>(gid, off, bsum, cursor, idx);

        int rgrid = (int)(((long long)NG * 64 + block - 1) / block);   // 25000
        reduce_kernel<<<rgrid, block, 0, stream>>>(feat, idx, off, bsum, cnt, means);

        int ggrid = (int)(((long long)NPTS * 32 + block - 1) / block); // 125000
        gather_mean_kernel<<<ggrid, block, 0, stream>>>(means, gid, out);
    } else {
        // fallback: harness-verified atomic implementation
        float* sums = (float*)d_ws;
        float* counts = sums + (long long)NG * CH;
        size_t zero_bytes = ((size_t)NG * CH + NG) * sizeof(float);
        hipMemsetAsync(d_ws, 0, zero_bytes, stream);

        long long total = (long long)NPTS * 32;
        int grid = (int)((total + block - 1) / block);
        accum_kernel<<<grid, block, 0, stream>>>(feat, gid, sums, counts);
        inv_kernel<<<(NG + block - 1) / block, block, 0, stream>>>(counts);
        gather_kernel<<<grid, block, 0, stream>>>(sums, counts, gid, out);
    }
}

// Round 3
// 964.284 us; speedup vs baseline: 2.5729x; 1.0679x over previous
//
#include <hip/hip_runtime.h>

#define NPTS 1000000
#define CH 128
#define NG 100000
#define SCAN_CHUNK 1024
#define NB ((NG + SCAN_CHUNK - 1) / SCAN_CHUNK)  // 98 blocks of 1024

// ============ fast path: counting sort + fused reduce-scatter ============

__global__ void hist_kernel(const int* __restrict__ gid, int* __restrict__ cnt) {
    int i = blockIdx.x * blockDim.x + threadIdx.x;
    if (i < NPTS) atomicAdd(&cnt[gid[i]], 1);
}

// per-1024-chunk exclusive scan (256 threads x 4 elements), block totals to bsum
__global__ void scan_blocks_kernel(const int* __restrict__ cnt, int* __restrict__ off,
                                   int* __restrict__ bsum) {
    __shared__ int lds[256];
    int t = threadIdx.x;
    int base = blockIdx.x * SCAN_CHUNK + t * 4;
    int a0 = 0, a1 = 0, a2 = 0, a3 = 0;
    if (base + 0 < NG) a0 = cnt[base + 0];
    if (base + 1 < NG) a1 = cnt[base + 1];
    if (base + 2 < NG) a2 = cnt[base + 2];
    if (base + 3 < NG) a3 = cnt[base + 3];
    lds[t] = a0 + a1 + a2 + a3;
    __syncthreads();
    for (int d = 1; d < 256; d <<= 1) {
        int v = (t >= d) ? lds[t - d] : 0;
        __syncthreads();
        lds[t] += v;
        __syncthreads();
    }
    int excl = (t == 0) ? 0 : lds[t - 1];
    if (t == 255) bsum[blockIdx.x] = lds[255];
    if (base + 0 < NG) off[base + 0] = excl;
    if (base + 1 < NG) off[base + 1] = excl + a0;
    if (base + 2 < NG) off[base + 2] = excl + a0 + a1;
    if (base + 3 < NG) off[base + 3] = excl + a0 + a1 + a2;
}

// exclusive scan of the 98 block totals (single block)
__global__ void scan_bsum_kernel(int* __restrict__ bsum) {
    __shared__ int lds[128];
    int t = threadIdx.x;
    int v = (t < NB) ? bsum[t] : 0;
    lds[t] = v;
    __syncthreads();
    for (int d = 1; d < 128; d <<= 1) {
        int u = (t >= d) ? lds[t - d] : 0;
        __syncthreads();
        lds[t] += u;
        __syncthreads();
    }
    int excl = (t == 0) ? 0 : lds[t - 1];
    if (t < NB) bsum[t] = excl;
}

// materialize final group offsets once; seed the fill cursor with them
__global__ void fixup_init_kernel(const int* __restrict__ off, const int* __restrict__ bsum,
                                  int* __restrict__ goff, int* __restrict__ cursor) {
    int i = blockIdx.x * blockDim.x + threadIdx.x;
    if (i < NG) {
        int v = off[i] + bsum[i >> 10];
        goff[i] = v;
        cursor[i] = v;
    }
}

// one atomicAdd returns the final slot directly
__global__ void fill_kernel(const int* __restrict__ gid, int* __restrict__ cursor,
                            int* __restrict__ idx) {
    int i = blockIdx.x * blockDim.x + threadIdx.x;
    if (i < NPTS) {
        int s = atomicAdd(&cursor[gid[i]], 1);
        idx[s] = i;
    }
}

// One 64-lane wave per group; lane owns 2 channels (float2 = 512B/row coalesced).
// Accumulates the group's points, then scatters the pre-divided mean straight to
// out[p] for every point p in the group — no means buffer, no gather pass.
// Point indices are broadcast from a single per-lane idx load via __shfl.
__global__ void reduce_scatter_kernel(const float* __restrict__ feat,
                                      const int* __restrict__ idx,
                                      const int* __restrict__ goff,
                                      const int* __restrict__ cnt,
                                      float* __restrict__ out) {
    long long t = (long long)blockIdx.x * blockDim.x + threadIdx.x;
    int g = (int)(t >> 6);
    int lane = (int)(t & 63);
    if (g >= NG) return;
    int o = goff[g];
    int n = cnt[g];
    if (n == 0) return;
    int pv = (lane < n) ? idx[o + lane] : 0;   // lane j holds idx of point j (j<64)
    int nw = (n < 64) ? n : 64;

    float2 a0 = make_float2(0.f, 0.f), a1 = make_float2(0.f, 0.f);
    int j = 0;
    for (; j + 2 <= nw; j += 2) {              // 2 independent loads in flight
        int p0 = __shfl(pv, j);
        int p1 = __shfl(pv, j + 1);
        float2 v0 = ((const float2*)(feat + (long long)p0 * CH))[lane];
        float2 v1 = ((const float2*)(feat + (long long)p1 * CH))[lane];
        a0.x += v0.x; a0.y += v0.y;
        a1.x += v1.x; a1.y += v1.y;
    }
    if (j < nw) {
        int p = __shfl(pv, j);
        float2 v = ((const float2*)(feat + (long long)p * CH))[lane];
        a0.x += v.x; a0.y += v.y;
    }
    for (int k = 64; k < n; ++k) {             // rare tail: groups larger than 64
        int p = idx[o + k];
        float2 v = ((const float2*)(feat + (long long)p * CH))[lane];
        a0.x += v.x; a0.y += v.y;
    }

    float inv = 1.0f / (float)n;
    float2 r = make_float2((a0.x + a1.x) * inv, (a0.y + a1.y) * inv);

    for (j = 0; j < nw; ++j) {                 // scatter mean to every member point
        int p = __shfl(pv, j);
        ((float2*)(out + (long long)p * CH))[lane] = r;
    }
    for (int k = 64; k < n; ++k) {
        int p = idx[o + k];
        ((float2*)(out + (long long)p * CH))[lane] = r;
    }
}

// ============ fallback path (harness-verified atomic version) ============

__global__ void accum_kernel(const float* __restrict__ feat,
                             const int* __restrict__ gid,
                             float* __restrict__ sums,
                             float* __restrict__ counts) {
    long long t = (long long)blockIdx.x * blockDim.x + threadIdx.x;
    int point = (int)(t >> 5);
    int sub = (int)(t & 31);
    if (point >= NPTS) return;
    int g = gid[point];
    const float4 v = ((const float4*)(feat + (long long)point * CH))[sub];
    float* dst = sums + (long long)g * CH + sub * 4;
    atomicAdd(dst + 0, v.x);
    atomicAdd(dst + 1, v.y);
    atomicAdd(dst + 2, v.z);
    atomicAdd(dst + 3, v.w);
    if (sub == 0) atomicAdd(counts + g, 1.0f);
}

__global__ void inv_kernel(float* __restrict__ counts) {
    int g = blockIdx.x * blockDim.x + threadIdx.x;
    if (g < NG) counts[g] = 1.0f / fmaxf(counts[g], 1.0f);
}

__global__ void gather_kernel(const float* __restrict__ sums,
                              const float* __restrict__ inv,
                              const int* __restrict__ gid,
                              float* __restrict__ out) {
    long long t = (long long)blockIdx.x * blockDim.x + threadIdx.x;
    int point = (int)(t >> 5);
    int sub = (int)(t & 31);
    if (point >= NPTS) return;
    int g = gid[point];
    float ic = inv[g];
    float4 v = ((const float4*)(sums + (long long)g * CH))[sub];
    v.x *= ic; v.y *= ic; v.z *= ic; v.w *= ic;
    ((float4*)(out + (long long)point * CH))[sub] = v;
}

// ================= launch =================

extern "C" void kernel_launch(void* const* d_in, const int* in_sizes, int n_in,
                              void* d_out, int out_size, void* d_ws, size_t ws_size,
                              hipStream_t stream) {
    const float* feat = (const float*)d_in[1];
    const int* gid = (const int*)d_in[2];
    float* out = (float*)d_out;

    // fast-path workspace layout (~5.7 MB, all 4-byte types)
    char* p = (char*)d_ws;
    int* idx    = (int*)p;  p += (size_t)NPTS * sizeof(int);  // 4.0 MB
    int* cnt    = (int*)p;  p += (size_t)NG * sizeof(int);
    int* off    = (int*)p;  p += (size_t)NG * sizeof(int);
    int* goff   = (int*)p;  p += (size_t)NG * sizeof(int);
    int* cursor = (int*)p;  p += (size_t)NG * sizeof(int);
    int* bsum   = (int*)p;  p += 128 * sizeof(int);
    size_t need = (size_t)(p - (char*)d_ws);

    const int block = 256;

    if (ws_size >= need) {
        hipMemsetAsync(cnt, 0, (size_t)NG * sizeof(int), stream);  // only cnt needs zeroing

        hist_kernel<<<(NPTS + block - 1) / block, block, 0, stream>>>(gid, cnt);
        scan_blocks_kernel<<<NB, 256, 0, stream>>>(cnt, off, bsum);
        scan_bsum_kernel<<<1, 128, 0, stream>>>(bsum);
        fixup_init_kernel<<<(NG + block - 1) / block, block, 0, stream>>>(off, bsum, goff, cursor);
        fill_kernel<<<(NPTS + block - 1) / block, block, 0, stream>>>(gid, cursor, idx);

        int rgrid = (int)(((long long)NG * 64 + block - 1) / block);  // 25000 blocks
        reduce_scatter_kernel<<<rgrid, block, 0, stream>>>(feat, idx, goff, cnt, out);
    } else {
        // fallback: harness-verified atomic implementation
        float* sums = (float*)d_ws;
        float* counts = sums + (long long)NG * CH;
        size_t zero_bytes = ((size_t)NG * CH + NG) * sizeof(float);
        hipMemsetAsync(d_ws, 0, zero_bytes, stream);

        long long total = (long long)NPTS * 32;
        int grid = (int)((total + block - 1) / block);
        accum_kernel<<<grid, block, 0, stream>>>(feat, gid, sums, counts);
        inv_kernel<<<(NG + block - 1) / block, block, 0, stream>>>(counts);
        gather_kernel<<<grid, block, 0, stream>>>(sums, counts, gid, out);
    }
}